// Round 6
// baseline (394.019 us; speedup 1.0000x reference)
//
#include <hip/hip_runtime.h>

#define IN_F 32
#define HID 64
#define OUTF 16
#define NSUB 8                     // sub-buckets per dst (XCD-locality heuristic)
#define SB_CAP 16                  // records per sub-bucket
#define OVF_CAP 65536
#define ORD_NEG_INF 0x007FFFFFu    // ordenc(-inf), "empty" marker

typedef _Float16 v8h __attribute__((ext_vector_type(8)));
typedef float v16f __attribute__((ext_vector_type(16)));

__device__ __forceinline__ unsigned ordenc(float v) {
  unsigned b = __float_as_uint(v);
  return (b & 0x80000000u) ? ~b : (b | 0x80000000u);
}
__device__ __forceinline__ float orddec(unsigned u) {
  unsigned b = (u & 0x80000000u) ? (u & 0x7FFFFFFFu) : ~u;
  return __uint_as_float(b);
}
__device__ __forceinline__ unsigned short f2h_bits(float f) {
  _Float16 h = (_Float16)f; unsigned short u; __builtin_memcpy(&u, &h, 2); return u;
}
__device__ __forceinline__ float h_bits2f(unsigned short u) {
  _Float16 h; __builtin_memcpy(&h, &u, 2); return (float)h;
}

// Fused: scatter (blocks [0, nSB)) + node_pre (blocks [nSB, nSB+512)).
// Scatter: 4 edges/thread, all atomics issued before ea loads (MLP).
// Q stored fp16 (6.4 MB; halves gather traffic in bucket_kernel, R3-verified).
__global__ __launch_bounds__(256) void pre_scatter_kernel(
    const float* __restrict__ x, const int* __restrict__ ei,
    const float* __restrict__ ea, const float* __restrict__ W1,
    const float* __restrict__ b1,
    float* __restrict__ P, _Float16* __restrict__ Q,
    uint2* __restrict__ rec, int* __restrict__ cnt,
    int* __restrict__ ovf, int* __restrict__ ovf_cnt,
    int E, int N, int nSB)
{
  if (blockIdx.x < (unsigned)nSB) {
    // ---------------- scatter ----------------
    const int t = threadIdx.x;
    const int base = blockIdx.x * 1024;
    const int g = blockIdx.x & (NSUB - 1);   // ~XCD id (perf heuristic only)
    int e[4], s[4], d[4], pos[4];
    bool v[4];
#pragma unroll
    for (int i = 0; i < 4; ++i) {
      e[i] = base + i * 256 + t;
      v[i] = e[i] < E;
      int ec = v[i] ? e[i] : 0;
      s[i] = ei[ec];
      d[i] = ei[(size_t)E + ec];
    }
#pragma unroll
    for (int i = 0; i < 4; ++i)
      pos[i] = v[i] ? atomicAdd(&cnt[d[i] * NSUB + g], 1) : SB_CAP;
    float a0[4], a1[4], a2[4];
#pragma unroll
    for (int i = 0; i < 4; ++i) {
      int ec = v[i] ? e[i] : 0;
      a0[i] = ea[ec * 3 + 0]; a1[i] = ea[ec * 3 + 1]; a2[i] = ea[ec * 3 + 2];
    }
#pragma unroll
    for (int i = 0; i < 4; ++i) {
      if (!v[i]) continue;
      if (pos[i] < SB_CAP) {
        uint2 r;
        r.x = (unsigned)s[i] | ((unsigned)f2h_bits(a0[i]) << 16);  // src < 65536
        r.y = (unsigned)f2h_bits(a1[i]) | ((unsigned)f2h_bits(a2[i]) << 16);
        rec[((size_t)d[i] * NSUB + g) * SB_CAP + pos[i]] = r;
      } else {
        int oi = atomicAdd(ovf_cnt, 1);
        if (oi < OVF_CAP) ovf[oi] = e[i];
      }
    }
    return;
  }
  // ---------------- node_pre ----------------
  const int lane = threadIdx.x & 63;
  float w1d[IN_F], w1b[IN_F];
#pragma unroll
  for (int c = 0; c < IN_F; ++c) {
    w1b[c] = W1[(IN_F + c) * HID + lane];
    w1d[c] = W1[c * HID + lane] - w1b[c];
  }
  const float b1v = b1[lane];
  int gw = __builtin_amdgcn_readfirstlane((((int)blockIdx.x - nSB) << 2) | (threadIdx.x >> 6));
  const int nwaves = 512 << 2;
  for (int n = gw; n < N; n += nwaves) {
    float p = b1v, q = 0.f;
#pragma unroll
    for (int c = 0; c < IN_F; ++c) {
      float xv = x[n * IN_F + c];
      p = fmaf(xv, w1d[c], p);
      q = fmaf(xv, w1b[c], q);
    }
    P[n * HID + lane] = p;
    Q[n * HID + lane] = (_Float16)q;
  }
}

// One wave per dst (R2 structure — best measured). 32-edge tiles via
// mfma_f32_32x32x16_f16: E[phases/dst] 2.54 -> 1.45 (R3/R5 post-mortems:
// bucket time tracks serial tile phases + per-item overhead, so fewer/wider
// phases at one item per dst is the only lever that reduces both).
// Layouts (by analogy with verified 16x16x32): A row=l&31,k=(l>>5)*8+j;
// B col=l&31, same k; C col=lane&31, row=(reg&3)+8*(reg>>2)+4*(lane>>5).
__global__ __launch_bounds__(256) void bucket_kernel(
    const uint2* __restrict__ rec, const int* __restrict__ cnt,
    const float* __restrict__ W1, const float* __restrict__ W2,
    const float* __restrict__ P, const _Float16* __restrict__ Q,
    unsigned* __restrict__ agg, int N)
{
  __shared__ __align__(16) _Float16 hB[4][32][72];     // [wave][edge][ch] 18 KB

  const int wave = threadIdx.x >> 6;
  const int lane = threadIdx.x & 63;
  const int lo5 = lane & 31;
  const int hi = lane >> 5;
  // channel this lane stores in the final permuted row write (bit-permutation,
  // matches C-layout: ch = t*32 + (reg&3) + 8*(reg>>2) + 4*hi with t=(lane>>4)&1, reg=lane&15)
  const int mych = (lane & 3) | ((lane >> 5) << 2) | (((lane >> 2) & 3) << 3) | (((lane >> 4) & 1) << 5);

  // A-operand: W2^T fragments for 32x32x16, fp16, loop-invariant.
  // a_frag[t][ks][j] = W2^T[ch_out = t*32 + lo5][ch = ks*16 + hi*8 + j]
  v8h a_frag[2][4];
#pragma unroll
  for (int t = 0; t < 2; ++t)
#pragma unroll
    for (int ks = 0; ks < 4; ++ks)
#pragma unroll
      for (int j = 0; j < 8; ++j)
        a_frag[t][ks][j] = (_Float16)W2[(ks * 16 + hi * 8 + j) * HID + t * 32 + lo5];

  const float w1c0 = W1[(2 * IN_F + 0) * HID + lane];
  const float w1c1 = W1[(2 * IN_F + 1) * HID + lane];
  const float w1c2 = W1[(2 * IN_F + 2) * HID + lane];

  const int gwave = __builtin_amdgcn_readfirstlane((blockIdx.x << 2) | wave);
  const int nw = gridDim.x << 2;

  int d = gwave;
  if (d >= N) return;   // waves are independent (no cross-wave LDS / syncthreads)

  // prefetch for dst dd: counts -> prefix -> record regs (lane i holds record i) + P row
  int m; uint2 r0, r1; float pP;
  auto prefetch = [&](int dd) {
    const uint4 ca = *(const uint4*)&cnt[(size_t)dd * NSUB];
    const uint4 cb = *(const uint4*)&cnt[(size_t)dd * NSUB + 4];
    int c0 = min((int)ca.x, SB_CAP), c1 = min((int)ca.y, SB_CAP);
    int c2 = min((int)ca.z, SB_CAP), c3 = min((int)ca.w, SB_CAP);
    int c4 = min((int)cb.x, SB_CAP), c5 = min((int)cb.y, SB_CAP);
    int c6 = min((int)cb.z, SB_CAP), c7 = min((int)cb.w, SB_CAP);
    int p1 = c0, p2 = p1 + c1, p3 = p2 + c2, p4 = p3 + c3;
    int p5 = p4 + c4, p6 = p5 + c5, p7 = p6 + c6;
    m = p7 + c7;
#pragma unroll
    for (int rr = 0; rr < 2; ++rr) {
      int i = rr * 64 + lane;
      if (i < m) {
        int g = 0, base = 0;
        if (i >= p1) { g = 1; base = p1; }
        if (i >= p2) { g = 2; base = p2; }
        if (i >= p3) { g = 3; base = p3; }
        if (i >= p4) { g = 4; base = p4; }
        if (i >= p5) { g = 5; base = p5; }
        if (i >= p6) { g = 6; base = p6; }
        if (i >= p7) { g = 7; base = p7; }
        uint2 rv = rec[((size_t)dd * NSUB + g) * SB_CAP + (i - base)];
        if (rr == 0) r0 = rv; else r1 = rv;
      }
    }
    pP = P[(size_t)dd * HID + lane];
  };

  prefetch(d);

  while (d < N) {
    const int dn = d + nw;
    const int m_cur = m;
    const float pvl = pP;
    uint2 ra = r0, rb = r1;   // active records for this dst

    if (m_cur > 0) {
      // ---- pad reg records: lanes >= m_cur get a copy of the last record ----
      {
        const int lm = m_cur - 1;
        unsigned rlx, rly;
        if (lm < 64) {
          rlx = (unsigned)__builtin_amdgcn_readlane((int)ra.x, lm);
          rly = (unsigned)__builtin_amdgcn_readlane((int)ra.y, lm);
        } else {
          rlx = (unsigned)__builtin_amdgcn_readlane((int)rb.x, lm & 63);
          rly = (unsigned)__builtin_amdgcn_readlane((int)rb.y, lm & 63);
        }
        if (lane >= m_cur)      { ra.x = rlx; ra.y = rly; }
        if (lane + 64 >= m_cur) { rb.x = rlx; rb.y = rly; }
      }

      // ---- tile-0 Q prefetch: 32 rows (uniform src -> saddr loads) ----
      float qv[32];
#pragma unroll
      for (int i = 0; i < 32; ++i) {
        unsigned sx = (unsigned)__builtin_amdgcn_readlane((int)ra.x, i) & 0xFFFFu;
        qv[i] = (float)Q[(size_t)sx * HID + lane];
      }

      // ---- prefetch next dst (counts -> records -> P), lands under MFMA work ----
      if (dn < N) prefetch(dn);

      // ---- process current dst: 32-edge MFMA tiles (ntile <= 4) ----
      float maxv[2][16];
#pragma unroll
      for (int t = 0; t < 2; ++t)
#pragma unroll
        for (int r = 0; r < 16; ++r) maxv[t][r] = -INFINITY;

      const int ntile = (m_cur + 31) >> 5;
      for (int tb = 0; tb < ntile; ++tb) {
        const unsigned rsx = (tb < 2) ? ra.x : rb.x;
        const unsigned rsy = (tb < 2) ? ra.y : rb.y;
        const int b0 = (tb & 1) << 5;
#pragma unroll
        for (int i = 0; i < 32; ++i) {
          const unsigned rx = (unsigned)__builtin_amdgcn_readlane((int)rsx, b0 + i);
          const unsigned ry = (unsigned)__builtin_amdgcn_readlane((int)rsy, b0 + i);
          float pre = pvl + qv[i];
          pre = fmaf(h_bits2f((unsigned short)(rx >> 16)), w1c0, pre);
          pre = fmaf(h_bits2f((unsigned short)(ry & 0xFFFFu)), w1c1, pre);
          pre = fmaf(h_bits2f((unsigned short)(ry >> 16)), w1c2, pre);
          hB[wave][i][lane] = (_Float16)fmaxf(pre, 0.f);
        }
        __builtin_amdgcn_wave_barrier();

        // B fragments: bf[ks][j] = h[edge=lo5][ch = ks*16 + hi*8 + j]
        const v8h bf0 = *(const v8h*)&hB[wave][lo5][0 + hi * 8];
        const v8h bf1 = *(const v8h*)&hB[wave][lo5][16 + hi * 8];
        const v8h bf2 = *(const v8h*)&hB[wave][lo5][32 + hi * 8];
        const v8h bf3 = *(const v8h*)&hB[wave][lo5][48 + hi * 8];

        // refill qv <- tile tb+1 (issued between ds_read and MFMA)
        if (tb + 1 < ntile) {
          const unsigned rnx = (tb + 1 < 2) ? ra.x : rb.x;
          const int bn = ((tb + 1) & 1) << 5;
#pragma unroll
          for (int i = 0; i < 32; ++i) {
            unsigned sx = (unsigned)__builtin_amdgcn_readlane((int)rnx, bn + i) & 0xFFFFu;
            qv[i] = (float)Q[(size_t)sx * HID + lane];
          }
        }

#pragma unroll
        for (int t = 0; t < 2; ++t) {
          v16f acc = (v16f)(0.f);
          acc = __builtin_amdgcn_mfma_f32_32x32x16_f16(a_frag[t][0], bf0, acc, 0, 0, 0);
          acc = __builtin_amdgcn_mfma_f32_32x32x16_f16(a_frag[t][1], bf1, acc, 0, 0, 0);
          acc = __builtin_amdgcn_mfma_f32_32x32x16_f16(a_frag[t][2], bf2, acc, 0, 0, 0);
          acc = __builtin_amdgcn_mfma_f32_32x32x16_f16(a_frag[t][3], bf3, acc, 0, 0, 0);
#pragma unroll
          for (int r = 0; r < 16; ++r) maxv[t][r] = fmaxf(maxv[t][r], acc[r]);
        }
        __builtin_amdgcn_wave_barrier();
      }

      // ---- butterfly max over the 32 edge-columns (lane bits 0..4) ----
#pragma unroll
      for (int t = 0; t < 2; ++t)
#pragma unroll
        for (int r = 0; r < 16; ++r) {
          float v = maxv[t][r];
          v = fmaxf(v, __shfl_xor(v, 1, 64));
          v = fmaxf(v, __shfl_xor(v, 2, 64));
          v = fmaxf(v, __shfl_xor(v, 4, 64));
          v = fmaxf(v, __shfl_xor(v, 8, 64));
          v = fmaxf(v, __shfl_xor(v, 16, 64));
          maxv[t][r] = v;
        }
      // lane stores maxv[(lane>>4)&1][lane&15] at channel mych
      float val = maxv[0][0];
#pragma unroll
      for (int t = 0; t < 2; ++t)
#pragma unroll
        for (int r = 0; r < 16; ++r)
          val = ((((lane >> 4) & 1) == t) && ((lane & 15) == r)) ? maxv[t][r] : val;
      agg[(size_t)d * HID + mych] = ordenc(val);
    } else {
      // empty dst; still run the next-dst prefetch to keep the pipeline primed
      if (dn < N) prefetch(dn);
      agg[(size_t)d * HID + lane] = ORD_NEG_INF;
    }
    d = dn;
  }
}

// Fallback for sub-bucket overflow (expected ~0 edges). fp32 P + fp16 Q path.
// atomicMax (runs after bucket_kernel's plain stores; ordenc(finite) > ORD_NEG_INF).
__global__ __launch_bounds__(256) void overflow_kernel(
    const int* __restrict__ ei, const float* __restrict__ ea,
    const float* __restrict__ W1, const float* __restrict__ W2,
    const float* __restrict__ P, const _Float16* __restrict__ Q,
    const int* __restrict__ ovf, const int* __restrict__ ovf_cnt,
    unsigned* __restrict__ agg, int E)
{
  __shared__ float hsh[4][HID];
  const int wave = threadIdx.x >> 6;
  const int lane = threadIdx.x & 63;

  int M = *ovf_cnt;
  if (M > OVF_CAP) M = OVF_CAP;
  if (M == 0) return;

  float w2r[HID];
#pragma unroll
  for (int j = 0; j < HID; ++j) w2r[j] = W2[j * HID + lane];
  const float w1c0 = W1[(2 * IN_F + 0) * HID + lane];
  const float w1c1 = W1[(2 * IN_F + 1) * HID + lane];
  const float w1c2 = W1[(2 * IN_F + 2) * HID + lane];

  const int gwave = __builtin_amdgcn_readfirstlane((blockIdx.x << 2) | wave);
  const int nw = gridDim.x << 2;
  for (int k = gwave; k < M; k += nw) {
    int e = ovf[k];
    int s = ei[e];
    int d = ei[(size_t)E + e];
    float pre = P[(size_t)d * HID + lane] + (float)Q[(size_t)s * HID + lane];
    pre = fmaf(ea[e * 3 + 0], w1c0, pre);
    pre = fmaf(ea[e * 3 + 1], w1c1, pre);
    pre = fmaf(ea[e * 3 + 2], w1c2, pre);
    hsh[wave][lane] = fmaxf(pre, 0.f);
    __builtin_amdgcn_wave_barrier();
    float mv = 0.f;
#pragma unroll
    for (int j = 0; j < HID; ++j) mv = fmaf(hsh[wave][j], w2r[j], mv);
    atomicMax(&agg[(size_t)d * HID + lane], ordenc(mv));
    __builtin_amdgcn_wave_barrier();
  }
}

// 16 nodes per block: decode agg (empty -> 0, else +b2), out = sigmoid(agg @ Wo + bo)
__global__ __launch_bounds__(256) void out_kernel(
    const unsigned* __restrict__ agg,
    const float* __restrict__ b2,
    const float* __restrict__ Wo, const float* __restrict__ bo,
    float* __restrict__ out, int N)
{
  __shared__ float Wos[HID * OUTF];
  __shared__ float bos[OUTF];
  __shared__ float b2s[HID];
  __shared__ float aggs[16][HID + 1];

  for (int i = threadIdx.x; i < HID * OUTF; i += 256) Wos[i] = Wo[i];
  if (threadIdx.x < OUTF) bos[threadIdx.x] = bo[threadIdx.x];
  if (threadIdx.x < HID) b2s[threadIdx.x] = b2[threadIdx.x];
  __syncthreads();

  const int nodeBase = blockIdx.x * 16;
  {
    int ln = threadIdx.x >> 4;
    int k0 = (threadIdx.x & 15) * 4;
    int n = nodeBase + ln;
    if (n < N) {
      const uint4 u = *(const uint4*)&agg[(size_t)n * HID + k0];
      aggs[ln][k0 + 0] = (u.x == ORD_NEG_INF) ? 0.f : orddec(u.x) + b2s[k0 + 0];
      aggs[ln][k0 + 1] = (u.y == ORD_NEG_INF) ? 0.f : orddec(u.y) + b2s[k0 + 1];
      aggs[ln][k0 + 2] = (u.z == ORD_NEG_INF) ? 0.f : orddec(u.z) + b2s[k0 + 2];
      aggs[ln][k0 + 3] = (u.w == ORD_NEG_INF) ? 0.f : orddec(u.w) + b2s[k0 + 3];
    }
  }
  __syncthreads();
  {
    int ln = threadIdx.x >> 4;
    int o = threadIdx.x & 15;
    int n = nodeBase + ln;
    if (n < N) {
      float acc = bos[o];
#pragma unroll
      for (int k = 0; k < HID; ++k) acc = fmaf(aggs[ln][k], Wos[k * OUTF + o], acc);
      out[n * OUTF + o] = 1.f / (1.f + __expf(-acc));
    }
  }
}

extern "C" void kernel_launch(void* const* d_in, const int* in_sizes, int n_in,
                              void* d_out, int out_size, void* d_ws, size_t ws_size,
                              hipStream_t stream) {
  const float* x  = (const float*)d_in[0];
  const int*   ei = (const int*)d_in[1];
  const float* ea = (const float*)d_in[2];
  const float* W1 = (const float*)d_in[3];
  const float* b1 = (const float*)d_in[4];
  const float* W2 = (const float*)d_in[5];
  const float* b2 = (const float*)d_in[6];
  const float* Wo = (const float*)d_in[7];
  const float* bo = (const float*)d_in[8];
  float* out = (float*)d_out;

  const int N = in_sizes[0] / IN_F;   // 50000
  const int E = in_sizes[1] / 2;      // 1600000

  // ws layout: P(12.8M) | Q fp16(6.4M) | agg(12.8M) | rec N*8*16 uint2(51.2M)
  //          | cnt N*8 i32(1.6M) | ovf_cnt | ovf   -> ~85 MB total (R3-proven)
  char* w = (char*)d_ws;
  float*     Pp  = (float*)w;                    w += (size_t)N * HID * 4;
  _Float16*  Qp  = (_Float16*)w;                 w += (size_t)N * HID * 2;
  unsigned*  agg = (unsigned*)w;                 w += (size_t)N * HID * 4;
  uint2*     rec = (uint2*)w;                    w += (size_t)N * NSUB * SB_CAP * 8;
  int*       cnt = (int*)w;                      w += (size_t)N * NSUB * 4;
  int*   ovf_cnt = (int*)w;                      w += 16;
  int*       ovf = (int*)w;

  hipMemsetAsync(cnt, 0, (size_t)N * NSUB * 4 + 16, stream);

  const int nSB = (E + 1023) / 1024;   // scatter blocks (4 edges/thread)
  pre_scatter_kernel<<<nSB + 512, 256, 0, stream>>>(
      x, ei, ea, W1, b1, Pp, Qp, rec, cnt, ovf, ovf_cnt, E, N, nSB);
  bucket_kernel<<<4096, 256, 0, stream>>>(rec, cnt, W1, W2, Pp, Qp, agg, N);
  overflow_kernel<<<256, 256, 0, stream>>>(ei, ea, W1, W2, Pp, Qp, ovf, ovf_cnt, agg, E);
  out_kernel<<<(N + 15) / 16, 256, 0, stream>>>(agg, b2, Wo, bo, out, N);
}

// Round 7
// 374.190 us; speedup vs baseline: 1.0530x; 1.0530x over previous
//
#include <hip/hip_runtime.h>

#define IN_F 32
#define HID 64
#define OUTF 16
#define NSUB 8                     // sub-buckets per dst
#define SB_CAP 8                   // records per sub-bucket (cap 64/dst total)
#define OVF_CAP 65536
#define ORD_NEG_INF 0x007FFFFFu    // ordenc(-inf), "empty" marker

typedef _Float16 v8h __attribute__((ext_vector_type(8)));
typedef float v4f __attribute__((ext_vector_type(4)));

__device__ __forceinline__ unsigned ordenc(float v) {
  unsigned b = __float_as_uint(v);
  return (b & 0x80000000u) ? ~b : (b | 0x80000000u);
}
__device__ __forceinline__ float orddec(unsigned u) {
  unsigned b = (u & 0x80000000u) ? (u & 0x7FFFFFFFu) : ~u;
  return __uint_as_float(b);
}
__device__ __forceinline__ unsigned short f2h_bits(float f) {
  _Float16 h = (_Float16)f; unsigned short u; __builtin_memcpy(&u, &h, 2); return u;
}
__device__ __forceinline__ float h_bits2f(unsigned short u) {
  _Float16 h; __builtin_memcpy(&h, &u, 2); return (float)h;
}

// Fused: scatter (blocks [0, nSB)) + node_pre (blocks [nSB, nSB+512)).
// Scatter: 8 edges/thread (deep atomic batching), atomics issued before ea loads.
// Q stored fp16 (6.4 MB; halves bucket gather traffic, R3-verified neutral-time).
__global__ __launch_bounds__(256) void pre_scatter_kernel(
    const float* __restrict__ x, const int* __restrict__ ei,
    const float* __restrict__ ea, const float* __restrict__ W1,
    const float* __restrict__ b1,
    float* __restrict__ P, _Float16* __restrict__ Q,
    uint2* __restrict__ rec, int* __restrict__ cnt,
    int* __restrict__ ovf, int* __restrict__ ovf_cnt,
    int E, int N, int nSB)
{
  if (blockIdx.x < (unsigned)nSB) {
    // ---------------- scatter ----------------
    const int t = threadIdx.x;
    const int base = blockIdx.x * 2048;
    const int g = blockIdx.x & (NSUB - 1);   // sub-bucket group (perf heuristic only)
    int e[8], s[8], d[8], pos[8];
    bool v[8];
#pragma unroll
    for (int i = 0; i < 8; ++i) {
      e[i] = base + i * 256 + t;
      v[i] = e[i] < E;
      int ec = v[i] ? e[i] : 0;
      s[i] = ei[ec];
      d[i] = ei[(size_t)E + ec];
    }
#pragma unroll
    for (int i = 0; i < 8; ++i)
      pos[i] = v[i] ? atomicAdd(&cnt[d[i] * NSUB + g], 1) : SB_CAP;
    float a0[8], a1[8], a2[8];
#pragma unroll
    for (int i = 0; i < 8; ++i) {
      int ec = v[i] ? e[i] : 0;
      a0[i] = ea[ec * 3 + 0]; a1[i] = ea[ec * 3 + 1]; a2[i] = ea[ec * 3 + 2];
    }
#pragma unroll
    for (int i = 0; i < 8; ++i) {
      if (!v[i]) continue;
      if (pos[i] < SB_CAP) {
        uint2 r;
        r.x = (unsigned)s[i] | ((unsigned)f2h_bits(a0[i]) << 16);  // src < 65536
        r.y = (unsigned)f2h_bits(a1[i]) | ((unsigned)f2h_bits(a2[i]) << 16);
        rec[((size_t)d[i] * NSUB + g) * SB_CAP + pos[i]] = r;
      } else {
        int oi = atomicAdd(ovf_cnt, 1);
        if (oi < OVF_CAP) ovf[oi] = e[i];
      }
    }
    return;
  }
  // ---------------- node_pre ----------------
  const int lane = threadIdx.x & 63;
  float w1d[IN_F], w1b[IN_F];
#pragma unroll
  for (int c = 0; c < IN_F; ++c) {
    w1b[c] = W1[(IN_F + c) * HID + lane];
    w1d[c] = W1[c * HID + lane] - w1b[c];
  }
  const float b1v = b1[lane];
  int gw = __builtin_amdgcn_readfirstlane((((int)blockIdx.x - nSB) << 2) | (threadIdx.x >> 6));
  const int nwaves = 512 << 2;
  for (int n = gw; n < N; n += nwaves) {
    float p = b1v, q = 0.f;
#pragma unroll
    for (int c = 0; c < IN_F; ++c) {
      float xv = x[n * IN_F + c];
      p = fmaf(xv, w1d[c], p);
      q = fmaf(xv, w1b[c], q);
    }
    P[n * HID + lane] = p;
    Q[n * HID + lane] = (_Float16)q;
  }
}

// One wave per dst, 16x16x32 MFMA (R2 structure — best measured). m <= 64:
// single-round record prefetch (one per-lane reg). Cross-dst qv0 prefetch:
// the NEXT dst's tile-0 Q batch is issued right after the current dst's tiles
// (its records already landed), hiding under the epilogue + loop turn.
__global__ __launch_bounds__(256) void bucket_kernel(
    const uint2* __restrict__ rec, const int* __restrict__ cnt,
    const float* __restrict__ W1, const float* __restrict__ W2,
    const float* __restrict__ P, const _Float16* __restrict__ Q,
    unsigned* __restrict__ agg, int N)
{
  __shared__ __align__(16) _Float16 hB[4][16][72];     // [wave][edge][ch]

  const int wave = threadIdx.x >> 6;
  const int lane = threadIdx.x & 63;
  const int quad = lane >> 4;
  const int eidx = lane & 15;
  // channel this lane stores in the final permuted row write
  const int mych = ((eidx >> 2) << 4) + (quad << 2) + (eidx & 3);

  // A-operand: W2^T fragments, fp16, loop-invariant (R2-verified).
  v8h a_frag[4][2];
#pragma unroll
  for (int t = 0; t < 4; ++t)
#pragma unroll
    for (int ks = 0; ks < 2; ++ks)
#pragma unroll
      for (int j = 0; j < 8; ++j)
        a_frag[t][ks][j] = (_Float16)W2[(ks * 32 + quad * 8 + j) * HID + t * 16 + eidx];

  const float w1c0 = W1[(2 * IN_F + 0) * HID + lane];
  const float w1c1 = W1[(2 * IN_F + 1) * HID + lane];
  const float w1c2 = W1[(2 * IN_F + 2) * HID + lane];

  const int gwave = __builtin_amdgcn_readfirstlane((blockIdx.x << 2) | wave);
  const int nw = gridDim.x << 2;

  int d = gwave;
  if (d >= N) return;   // waves are independent (no cross-wave LDS / syncthreads)

  // prefetch for dst dd: counts -> prefix -> record reg (lane i holds record i) + P row
  int m; uint2 r0; float pP;
  auto prefetch = [&](int dd) {
    const uint4 ca = *(const uint4*)&cnt[(size_t)dd * NSUB];
    const uint4 cb = *(const uint4*)&cnt[(size_t)dd * NSUB + 4];
    int c0 = min((int)ca.x, SB_CAP), c1 = min((int)ca.y, SB_CAP);
    int c2 = min((int)ca.z, SB_CAP), c3 = min((int)ca.w, SB_CAP);
    int c4 = min((int)cb.x, SB_CAP), c5 = min((int)cb.y, SB_CAP);
    int c6 = min((int)cb.z, SB_CAP), c7 = min((int)cb.w, SB_CAP);
    int p1 = c0, p2 = p1 + c1, p3 = p2 + c2, p4 = p3 + c3;
    int p5 = p4 + c4, p6 = p5 + c5, p7 = p6 + c6;
    m = p7 + c7;                                  // <= 64
    if (lane < m) {
      int g = 0, base = 0;
      if (lane >= p1) { g = 1; base = p1; }
      if (lane >= p2) { g = 2; base = p2; }
      if (lane >= p3) { g = 3; base = p3; }
      if (lane >= p4) { g = 4; base = p4; }
      if (lane >= p5) { g = 5; base = p5; }
      if (lane >= p6) { g = 6; base = p6; }
      if (lane >= p7) { g = 7; base = p7; }
      r0 = rec[((size_t)dd * NSUB + g) * SB_CAP + (lane - base)];
    }
    pP = P[(size_t)dd * HID + lane];
  };

  // pad r0 in place (lanes >= m get last record) and issue tile-0 Q batch -> qv0
  float qv0[16];
  auto pad_and_qv0 = [&]() {
    const int lm = m - 1;
    const unsigned rlx = (unsigned)__builtin_amdgcn_readlane((int)r0.x, lm);
    const unsigned rly = (unsigned)__builtin_amdgcn_readlane((int)r0.y, lm);
    if (lane >= m) { r0.x = rlx; r0.y = rly; }
#pragma unroll
    for (int i = 0; i < 16; ++i) {
      unsigned sx = (unsigned)__builtin_amdgcn_readlane((int)r0.x, i) & 0xFFFFu;
      qv0[i] = (float)Q[(size_t)sx * HID + lane];
    }
  };

  prefetch(d);
  if (m > 0) pad_and_qv0();

  while (d < N) {
    const int dn = d + nw;
    const int m_cur = m;
    const float pvl = pP;
    const uint2 ra = r0;   // active (padded) records for this dst

    if (m_cur > 0) {
      float qv[16];
#pragma unroll
      for (int i = 0; i < 16; ++i) qv[i] = qv0[i];

      // ---- prefetch next dst (counts -> records -> P), lands under tile work ----
      if (dn < N) prefetch(dn);

      // ---- process current dst: 16-edge MFMA tiles (ntile <= 4) ----
      float maxv[4][4];
#pragma unroll
      for (int t = 0; t < 4; ++t)
#pragma unroll
        for (int r = 0; r < 4; ++r) maxv[t][r] = -INFINITY;

      const int ntile = (m_cur + 15) >> 4;
      for (int tb = 0; tb < ntile; ++tb) {
        const int b16 = tb << 4;
#pragma unroll
        for (int i = 0; i < 16; ++i) {
          const unsigned rx = (unsigned)__builtin_amdgcn_readlane((int)ra.x, b16 + i);
          const unsigned ry = (unsigned)__builtin_amdgcn_readlane((int)ra.y, b16 + i);
          float pre = pvl + qv[i];
          pre = fmaf(h_bits2f((unsigned short)(rx >> 16)), w1c0, pre);
          pre = fmaf(h_bits2f((unsigned short)(ry & 0xFFFFu)), w1c1, pre);
          pre = fmaf(h_bits2f((unsigned short)(ry >> 16)), w1c2, pre);
          hB[wave][i][lane] = (_Float16)fmaxf(pre, 0.f);
        }
        __builtin_amdgcn_wave_barrier();

        const v8h bf0 = *(const v8h*)&hB[wave][eidx][quad * 8];
        const v8h bf1 = *(const v8h*)&hB[wave][eidx][32 + quad * 8];
        // refill qv <- tile tb+1 (issued between ds_read and MFMA)
        if (tb + 1 < ntile) {
          const int bn = (tb + 1) << 4;
#pragma unroll
          for (int i = 0; i < 16; ++i) {
            unsigned sx = (unsigned)__builtin_amdgcn_readlane((int)ra.x, bn + i) & 0xFFFFu;
            qv[i] = (float)Q[(size_t)sx * HID + lane];
          }
        }
#pragma unroll
        for (int t = 0; t < 4; ++t) {
          v4f acc = (v4f){0.f, 0.f, 0.f, 0.f};
          acc = __builtin_amdgcn_mfma_f32_16x16x32_f16(a_frag[t][0], bf0, acc, 0, 0, 0);
          acc = __builtin_amdgcn_mfma_f32_16x16x32_f16(a_frag[t][1], bf1, acc, 0, 0, 0);
#pragma unroll
          for (int r = 0; r < 4; ++r) maxv[t][r] = fmaxf(maxv[t][r], acc[r]);
        }
        __builtin_amdgcn_wave_barrier();
      }

      // ---- cross-dst: pad next records + issue its tile-0 Q batch NOW,
      //      so it hides under the epilogue + loop turn ----
      if (dn < N && m > 0) pad_and_qv0();

      // ---- butterfly max over the 16 edge-columns, direct permuted row store ----
#pragma unroll
      for (int t = 0; t < 4; ++t)
#pragma unroll
        for (int r = 0; r < 4; ++r) {
          float v = maxv[t][r];
          v = fmaxf(v, __shfl_xor(v, 1, 64));
          v = fmaxf(v, __shfl_xor(v, 2, 64));
          v = fmaxf(v, __shfl_xor(v, 4, 64));
          v = fmaxf(v, __shfl_xor(v, 8, 64));
          maxv[t][r] = v;
        }
      float val = maxv[0][0];
#pragma unroll
      for (int t = 0; t < 4; ++t)
#pragma unroll
        for (int r = 0; r < 4; ++r)
          val = (eidx == t * 4 + r) ? maxv[t][r] : val;
      agg[(size_t)d * HID + mych] = ordenc(val);   // permutation within one 256B row
    } else {
      // empty dst; keep the pipeline invariant (next dst padded + qv0 ready)
      if (dn < N) { prefetch(dn); if (m > 0) pad_and_qv0(); }
      agg[(size_t)d * HID + lane] = ORD_NEG_INF;
    }
    d = dn;
  }
}

// Fallback for sub-bucket overflow (expected ~7K edges). fp32 P + fp16 Q path.
// atomicMax (runs after bucket_kernel's plain stores; ordenc(finite) > ORD_NEG_INF).
__global__ __launch_bounds__(256) void overflow_kernel(
    const int* __restrict__ ei, const float* __restrict__ ea,
    const float* __restrict__ W1, const float* __restrict__ W2,
    const float* __restrict__ P, const _Float16* __restrict__ Q,
    const int* __restrict__ ovf, const int* __restrict__ ovf_cnt,
    unsigned* __restrict__ agg, int E)
{
  __shared__ float hsh[4][HID];
  const int wave = threadIdx.x >> 6;
  const int lane = threadIdx.x & 63;

  int M = *ovf_cnt;
  if (M > OVF_CAP) M = OVF_CAP;
  if (M == 0) return;

  float w2r[HID];
#pragma unroll
  for (int j = 0; j < HID; ++j) w2r[j] = W2[j * HID + lane];
  const float w1c0 = W1[(2 * IN_F + 0) * HID + lane];
  const float w1c1 = W1[(2 * IN_F + 1) * HID + lane];
  const float w1c2 = W1[(2 * IN_F + 2) * HID + lane];

  const int gwave = __builtin_amdgcn_readfirstlane((blockIdx.x << 2) | wave);
  const int nw = gridDim.x << 2;
  for (int k = gwave; k < M; k += nw) {
    int e = ovf[k];
    int s = ei[e];
    int d = ei[(size_t)E + e];
    float pre = P[(size_t)d * HID + lane] + (float)Q[(size_t)s * HID + lane];
    pre = fmaf(ea[e * 3 + 0], w1c0, pre);
    pre = fmaf(ea[e * 3 + 1], w1c1, pre);
    pre = fmaf(ea[e * 3 + 2], w1c2, pre);
    hsh[wave][lane] = fmaxf(pre, 0.f);
    __builtin_amdgcn_wave_barrier();
    float mv = 0.f;
#pragma unroll
    for (int j = 0; j < HID; ++j) mv = fmaf(hsh[wave][j], w2r[j], mv);
    atomicMax(&agg[(size_t)d * HID + lane], ordenc(mv));
    __builtin_amdgcn_wave_barrier();
  }
}

// 16 nodes per block: decode agg (empty -> 0, else +b2), out = sigmoid(agg @ Wo + bo)
__global__ __launch_bounds__(256) void out_kernel(
    const unsigned* __restrict__ agg,
    const float* __restrict__ b2,
    const float* __restrict__ Wo, const float* __restrict__ bo,
    float* __restrict__ out, int N)
{
  __shared__ float Wos[HID * OUTF];
  __shared__ float bos[OUTF];
  __shared__ float b2s[HID];
  __shared__ float aggs[16][HID + 1];

  for (int i = threadIdx.x; i < HID * OUTF; i += 256) Wos[i] = Wo[i];
  if (threadIdx.x < OUTF) bos[threadIdx.x] = bo[threadIdx.x];
  if (threadIdx.x < HID) b2s[threadIdx.x] = b2[threadIdx.x];
  __syncthreads();

  const int nodeBase = blockIdx.x * 16;
  {
    int ln = threadIdx.x >> 4;
    int k0 = (threadIdx.x & 15) * 4;
    int n = nodeBase + ln;
    if (n < N) {
      const uint4 u = *(const uint4*)&agg[(size_t)n * HID + k0];
      aggs[ln][k0 + 0] = (u.x == ORD_NEG_INF) ? 0.f : orddec(u.x) + b2s[k0 + 0];
      aggs[ln][k0 + 1] = (u.y == ORD_NEG_INF) ? 0.f : orddec(u.y) + b2s[k0 + 1];
      aggs[ln][k0 + 2] = (u.z == ORD_NEG_INF) ? 0.f : orddec(u.z) + b2s[k0 + 2];
      aggs[ln][k0 + 3] = (u.w == ORD_NEG_INF) ? 0.f : orddec(u.w) + b2s[k0 + 3];
    }
  }
  __syncthreads();
  {
    int ln = threadIdx.x >> 4;
    int o = threadIdx.x & 15;
    int n = nodeBase + ln;
    if (n < N) {
      float acc = bos[o];
#pragma unroll
      for (int k = 0; k < HID; ++k) acc = fmaf(aggs[ln][k], Wos[k * OUTF + o], acc);
      out[n * OUTF + o] = 1.f / (1.f + __expf(-acc));
    }
  }
}

extern "C" void kernel_launch(void* const* d_in, const int* in_sizes, int n_in,
                              void* d_out, int out_size, void* d_ws, size_t ws_size,
                              hipStream_t stream) {
  const float* x  = (const float*)d_in[0];
  const int*   ei = (const int*)d_in[1];
  const float* ea = (const float*)d_in[2];
  const float* W1 = (const float*)d_in[3];
  const float* b1 = (const float*)d_in[4];
  const float* W2 = (const float*)d_in[5];
  const float* b2 = (const float*)d_in[6];
  const float* Wo = (const float*)d_in[7];
  const float* bo = (const float*)d_in[8];
  float* out = (float*)d_out;

  const int N = in_sizes[0] / IN_F;   // 50000
  const int E = in_sizes[1] / 2;      // 1600000

  // ws layout: P(12.8M) | Q fp16(6.4M) | agg(12.8M) | rec N*8*8 uint2(25.6M)
  //          | cnt N*8 i32(1.6M) | ovf_cnt | ovf   -> ~59.5 MB total
  char* w = (char*)d_ws;
  float*     Pp  = (float*)w;                    w += (size_t)N * HID * 4;
  _Float16*  Qp  = (_Float16*)w;                 w += (size_t)N * HID * 2;
  unsigned*  agg = (unsigned*)w;                 w += (size_t)N * HID * 4;
  uint2*     rec = (uint2*)w;                    w += (size_t)N * NSUB * SB_CAP * 8;
  int*       cnt = (int*)w;                      w += (size_t)N * NSUB * 4;
  int*   ovf_cnt = (int*)w;                      w += 16;
  int*       ovf = (int*)w;

  hipMemsetAsync(cnt, 0, (size_t)N * NSUB * 4 + 16, stream);

  const int nSB = (E + 2047) / 2048;   // scatter blocks (8 edges/thread)
  pre_scatter_kernel<<<nSB + 512, 256, 0, stream>>>(
      x, ei, ea, W1, b1, Pp, Qp, rec, cnt, ovf, ovf_cnt, E, N, nSB);
  bucket_kernel<<<4096, 256, 0, stream>>>(rec, cnt, W1, W2, Pp, Qp, agg, N);
  overflow_kernel<<<256, 256, 0, stream>>>(ei, ea, W1, W2, Pp, Qp, ovf, ovf_cnt, agg, E);
  out_kernel<<<(N + 15) / 16, 256, 0, stream>>>(agg, b2, Wo, bo, out, N);
}

// Round 8
// 290.044 us; speedup vs baseline: 1.3585x; 1.2901x over previous
//
#include <hip/hip_runtime.h>

#define IN_F 32
#define HID 64
#define OUTF 16
#define NSUB 8                     // sub-buckets per dst (XCD-locality heuristic)
#define SB_CAP 16                  // records per sub-bucket
#define OVF_CAP 65536
#define ORD_NEG_INF 0x007FFFFFu    // ordenc(-inf), "empty" marker

typedef _Float16 v8h __attribute__((ext_vector_type(8)));
typedef float v4f __attribute__((ext_vector_type(4)));

__device__ __forceinline__ unsigned ordenc(float v) {
  unsigned b = __float_as_uint(v);
  return (b & 0x80000000u) ? ~b : (b | 0x80000000u);
}
__device__ __forceinline__ float orddec(unsigned u) {
  unsigned b = (u & 0x80000000u) ? (u & 0x7FFFFFFFu) : ~u;
  return __uint_as_float(b);
}
__device__ __forceinline__ unsigned short f2h_bits(float f) {
  _Float16 h = (_Float16)f; unsigned short u; __builtin_memcpy(&u, &h, 2); return u;
}
__device__ __forceinline__ float h_bits2f(unsigned short u) {
  _Float16 h; __builtin_memcpy(&h, &u, 2); return (float)h;
}

// Fused: scatter (blocks [0, nSB)) + node_pre (blocks [nSB, nSB+512)).
// R0-verified config: 4 edges/thread, SB_CAP=16 (overflow ~= 0 -> no contended
// ovf_cnt atomics; R7's 8/thread + SB_CAP=8 regressed 110->150).
// Q stored fp16 (halves bucket gather traffic, R3-verified time-neutral).
__global__ __launch_bounds__(256) void pre_scatter_kernel(
    const float* __restrict__ x, const int* __restrict__ ei,
    const float* __restrict__ ea, const float* __restrict__ W1,
    const float* __restrict__ b1,
    float* __restrict__ P, _Float16* __restrict__ Q,
    uint2* __restrict__ rec, int* __restrict__ cnt,
    int* __restrict__ ovf, int* __restrict__ ovf_cnt,
    int E, int N, int nSB)
{
  if (blockIdx.x < (unsigned)nSB) {
    // ---------------- scatter ----------------
    const int t = threadIdx.x;
    const int base = blockIdx.x * 1024;
    const int g = blockIdx.x & (NSUB - 1);   // ~XCD id (perf heuristic only)
    int e[4], s[4], d[4], pos[4];
    bool v[4];
#pragma unroll
    for (int i = 0; i < 4; ++i) {
      e[i] = base + i * 256 + t;
      v[i] = e[i] < E;
      int ec = v[i] ? e[i] : 0;
      s[i] = ei[ec];
      d[i] = ei[(size_t)E + ec];
    }
#pragma unroll
    for (int i = 0; i < 4; ++i)
      pos[i] = v[i] ? atomicAdd(&cnt[d[i] * NSUB + g], 1) : SB_CAP;
    float a0[4], a1[4], a2[4];
#pragma unroll
    for (int i = 0; i < 4; ++i) {
      int ec = v[i] ? e[i] : 0;
      a0[i] = ea[ec * 3 + 0]; a1[i] = ea[ec * 3 + 1]; a2[i] = ea[ec * 3 + 2];
    }
#pragma unroll
    for (int i = 0; i < 4; ++i) {
      if (!v[i]) continue;
      if (pos[i] < SB_CAP) {
        uint2 r;
        r.x = (unsigned)s[i] | ((unsigned)f2h_bits(a0[i]) << 16);  // src < 65536
        r.y = (unsigned)f2h_bits(a1[i]) | ((unsigned)f2h_bits(a2[i]) << 16);
        rec[((size_t)d[i] * NSUB + g) * SB_CAP + pos[i]] = r;
      } else {
        int oi = atomicAdd(ovf_cnt, 1);
        if (oi < OVF_CAP) ovf[oi] = e[i];
      }
    }
    return;
  }
  // ---------------- node_pre ----------------
  const int lane = threadIdx.x & 63;
  float w1d[IN_F], w1b[IN_F];
#pragma unroll
  for (int c = 0; c < IN_F; ++c) {
    w1b[c] = W1[(IN_F + c) * HID + lane];
    w1d[c] = W1[c * HID + lane] - w1b[c];
  }
  const float b1v = b1[lane];
  int gw = __builtin_amdgcn_readfirstlane((((int)blockIdx.x - nSB) << 2) | (threadIdx.x >> 6));
  const int nwaves = 512 << 2;
  for (int n = gw; n < N; n += nwaves) {
    float p = b1v, q = 0.f;
#pragma unroll
    for (int c = 0; c < IN_F; ++c) {
      float xv = x[n * IN_F + c];
      p = fmaf(xv, w1d[c], p);
      q = fmaf(xv, w1b[c], q);
    }
    P[n * HID + lane] = p;
    Q[n * HID + lane] = (_Float16)q;
  }
}

// One wave per dst, 16x16x32 MFMA, register-held records + v_readlane broadcast
// (R2 structure — best measured, 112 us). fp16 Q (R3: FETCH halved, time-neutral).
// New vs R2/R3: second record-load round + its prefix chain only when m > 64
// (Pois(32) tail ~3e-7) — wave-uniform rare branch saves ~40-60 VALU/dst.
// No pair-rounding (R3's +21% phantom tiles regression removed).
__global__ __launch_bounds__(256) void bucket_kernel(
    const uint2* __restrict__ rec, const int* __restrict__ cnt,
    const float* __restrict__ W1, const float* __restrict__ W2,
    const float* __restrict__ P, const _Float16* __restrict__ Q,
    unsigned* __restrict__ agg, int N)
{
  __shared__ __align__(16) _Float16 hB[4][16][72];     // [wave][edge][ch]

  const int wave = threadIdx.x >> 6;
  const int lane = threadIdx.x & 63;
  const int quad = lane >> 4;
  const int eidx = lane & 15;
  // channel this lane stores in the final permuted row write
  const int mych = ((eidx >> 2) << 4) + (quad << 2) + (eidx & 3);

  // A-operand: W2^T fragments, fp16, loop-invariant (R2-verified).
  v8h a_frag[4][2];
#pragma unroll
  for (int t = 0; t < 4; ++t)
#pragma unroll
    for (int ks = 0; ks < 2; ++ks)
#pragma unroll
      for (int j = 0; j < 8; ++j)
        a_frag[t][ks][j] = (_Float16)W2[(ks * 32 + quad * 8 + j) * HID + t * 16 + eidx];

  const float w1c0 = W1[(2 * IN_F + 0) * HID + lane];
  const float w1c1 = W1[(2 * IN_F + 1) * HID + lane];
  const float w1c2 = W1[(2 * IN_F + 2) * HID + lane];

  const int gwave = __builtin_amdgcn_readfirstlane((blockIdx.x << 2) | wave);
  const int nw = gridDim.x << 2;

  int d = gwave;
  if (d >= N) return;   // waves are independent (no cross-wave LDS / syncthreads)

  // prefetch for dst dd: counts -> prefix -> record regs (lane i holds record i) + P row.
  // round 2 (records 64..m) only when m > 64 (rare).
  int m; uint2 r0, r1; float pP;
  auto prefetch = [&](int dd) {
    const uint4 ca = *(const uint4*)&cnt[(size_t)dd * NSUB];
    const uint4 cb = *(const uint4*)&cnt[(size_t)dd * NSUB + 4];
    int c0 = min((int)ca.x, SB_CAP), c1 = min((int)ca.y, SB_CAP);
    int c2 = min((int)ca.z, SB_CAP), c3 = min((int)ca.w, SB_CAP);
    int c4 = min((int)cb.x, SB_CAP), c5 = min((int)cb.y, SB_CAP);
    int c6 = min((int)cb.z, SB_CAP), c7 = min((int)cb.w, SB_CAP);
    int p1 = c0, p2 = p1 + c1, p3 = p2 + c2, p4 = p3 + c3;
    int p5 = p4 + c4, p6 = p5 + c5, p7 = p6 + c6;
    m = p7 + c7;
    {
      const int i = lane;
      if (i < m) {
        int g = 0, base = 0;
        if (i >= p1) { g = 1; base = p1; }
        if (i >= p2) { g = 2; base = p2; }
        if (i >= p3) { g = 3; base = p3; }
        if (i >= p4) { g = 4; base = p4; }
        if (i >= p5) { g = 5; base = p5; }
        if (i >= p6) { g = 6; base = p6; }
        if (i >= p7) { g = 7; base = p7; }
        r0 = rec[((size_t)dd * NSUB + g) * SB_CAP + (i - base)];
      }
    }
    if (m > 64) {   // wave-uniform rare branch
      const int i = 64 + lane;
      if (i < m) {
        int g = 0, base = 0;
        if (i >= p1) { g = 1; base = p1; }
        if (i >= p2) { g = 2; base = p2; }
        if (i >= p3) { g = 3; base = p3; }
        if (i >= p4) { g = 4; base = p4; }
        if (i >= p5) { g = 5; base = p5; }
        if (i >= p6) { g = 6; base = p6; }
        if (i >= p7) { g = 7; base = p7; }
        r1 = rec[((size_t)dd * NSUB + g) * SB_CAP + (i - base)];
      }
    }
    pP = P[(size_t)dd * HID + lane];
  };

  prefetch(d);

  while (d < N) {
    const int dn = d + nw;
    const int m_cur = m;
    const float pvl = pP;
    uint2 ra = r0, rb = r1;   // active records for this dst

    if (m_cur > 0) {
      // ---- pad reg records: lanes >= m_cur get a copy of the last record.
      //      (when m<=64, rb is fully overwritten by broadcast -> r1 garbage is dead)
      {
        const int lm = m_cur - 1;
        unsigned rlx, rly;
        if (lm < 64) {
          rlx = (unsigned)__builtin_amdgcn_readlane((int)ra.x, lm);
          rly = (unsigned)__builtin_amdgcn_readlane((int)ra.y, lm);
        } else {
          rlx = (unsigned)__builtin_amdgcn_readlane((int)rb.x, lm & 63);
          rly = (unsigned)__builtin_amdgcn_readlane((int)rb.y, lm & 63);
        }
        if (lane >= m_cur)      { ra.x = rlx; ra.y = rly; }
        if (lane + 64 >= m_cur) { rb.x = rlx; rb.y = rly; }
      }

      // ---- tile-0 Q prefetch (uniform src -> saddr loads) ----
      float qv[16];
#pragma unroll
      for (int i = 0; i < 16; ++i) {
        unsigned sx = (unsigned)__builtin_amdgcn_readlane((int)ra.x, i) & 0xFFFFu;
        qv[i] = (float)Q[(size_t)sx * HID + lane];
      }

      // ---- prefetch next dst (counts -> records -> P), lands under MFMA work ----
      if (dn < N) prefetch(dn);

      // ---- process current dst: 16-edge MFMA tiles ----
      float maxv[4][4];
#pragma unroll
      for (int t = 0; t < 4; ++t)
#pragma unroll
        for (int r = 0; r < 4; ++r) maxv[t][r] = -INFINITY;

      const int ntile = (m_cur + 15) >> 4;
      for (int tb = 0; tb < ntile; ++tb) {
        const unsigned rsx = (tb < 4) ? ra.x : rb.x;
        const unsigned rsy = (tb < 4) ? ra.y : rb.y;
        const int b16 = (tb & 3) << 4;
#pragma unroll
        for (int i = 0; i < 16; ++i) {
          const unsigned rx = (unsigned)__builtin_amdgcn_readlane((int)rsx, b16 + i);
          const unsigned ry = (unsigned)__builtin_amdgcn_readlane((int)rsy, b16 + i);
          float pre = pvl + qv[i];
          pre = fmaf(h_bits2f((unsigned short)(rx >> 16)), w1c0, pre);
          pre = fmaf(h_bits2f((unsigned short)(ry & 0xFFFFu)), w1c1, pre);
          pre = fmaf(h_bits2f((unsigned short)(ry >> 16)), w1c2, pre);
          hB[wave][i][lane] = (_Float16)fmaxf(pre, 0.f);
        }
        __builtin_amdgcn_wave_barrier();

        const v8h bf0 = *(const v8h*)&hB[wave][eidx][quad * 8];
        const v8h bf1 = *(const v8h*)&hB[wave][eidx][32 + quad * 8];
        // refill qv <- tile tb+1 (issued between ds_read and MFMA)
        if (tb + 1 < ntile) {
          const unsigned rnx = (tb + 1 < 4) ? ra.x : rb.x;
          const int bn = ((tb + 1) & 3) << 4;
#pragma unroll
          for (int i = 0; i < 16; ++i) {
            unsigned sx = (unsigned)__builtin_amdgcn_readlane((int)rnx, bn + i) & 0xFFFFu;
            qv[i] = (float)Q[(size_t)sx * HID + lane];
          }
        }
#pragma unroll
        for (int t = 0; t < 4; ++t) {
          v4f acc = (v4f){0.f, 0.f, 0.f, 0.f};
          acc = __builtin_amdgcn_mfma_f32_16x16x32_f16(a_frag[t][0], bf0, acc, 0, 0, 0);
          acc = __builtin_amdgcn_mfma_f32_16x16x32_f16(a_frag[t][1], bf1, acc, 0, 0, 0);
#pragma unroll
          for (int r = 0; r < 4; ++r) maxv[t][r] = fmaxf(maxv[t][r], acc[r]);
        }
        __builtin_amdgcn_wave_barrier();
      }

      // ---- butterfly max over the 16 edge-columns, direct permuted row store ----
#pragma unroll
      for (int t = 0; t < 4; ++t)
#pragma unroll
        for (int r = 0; r < 4; ++r) {
          float v = maxv[t][r];
          v = fmaxf(v, __shfl_xor(v, 1, 64));
          v = fmaxf(v, __shfl_xor(v, 2, 64));
          v = fmaxf(v, __shfl_xor(v, 4, 64));
          v = fmaxf(v, __shfl_xor(v, 8, 64));
          maxv[t][r] = v;
        }
      float val = maxv[0][0];
#pragma unroll
      for (int t = 0; t < 4; ++t)
#pragma unroll
        for (int r = 0; r < 4; ++r)
          val = (eidx == t * 4 + r) ? maxv[t][r] : val;
      agg[(size_t)d * HID + mych] = ordenc(val);   // permutation within one 256B row
    } else {
      // empty dst; still run the next-dst prefetch to keep the pipeline primed
      if (dn < N) prefetch(dn);
      agg[(size_t)d * HID + lane] = ORD_NEG_INF;
    }
    d = dn;
  }
}

// Fallback for sub-bucket overflow (expected ~0 edges). fp32 P + fp16 Q path.
// atomicMax (runs after bucket_kernel's plain stores; ordenc(finite) > ORD_NEG_INF).
__global__ __launch_bounds__(256) void overflow_kernel(
    const int* __restrict__ ei, const float* __restrict__ ea,
    const float* __restrict__ W1, const float* __restrict__ W2,
    const float* __restrict__ P, const _Float16* __restrict__ Q,
    const int* __restrict__ ovf, const int* __restrict__ ovf_cnt,
    unsigned* __restrict__ agg, int E)
{
  __shared__ float hsh[4][HID];
  const int wave = threadIdx.x >> 6;
  const int lane = threadIdx.x & 63;

  int M = *ovf_cnt;
  if (M > OVF_CAP) M = OVF_CAP;
  if (M == 0) return;

  float w2r[HID];
#pragma unroll
  for (int j = 0; j < HID; ++j) w2r[j] = W2[j * HID + lane];
  const float w1c0 = W1[(2 * IN_F + 0) * HID + lane];
  const float w1c1 = W1[(2 * IN_F + 1) * HID + lane];
  const float w1c2 = W1[(2 * IN_F + 2) * HID + lane];

  const int gwave = __builtin_amdgcn_readfirstlane((blockIdx.x << 2) | wave);
  const int nw = gridDim.x << 2;
  for (int k = gwave; k < M; k += nw) {
    int e = ovf[k];
    int s = ei[e];
    int d = ei[(size_t)E + e];
    float pre = P[(size_t)d * HID + lane] + (float)Q[(size_t)s * HID + lane];
    pre = fmaf(ea[e * 3 + 0], w1c0, pre);
    pre = fmaf(ea[e * 3 + 1], w1c1, pre);
    pre = fmaf(ea[e * 3 + 2], w1c2, pre);
    hsh[wave][lane] = fmaxf(pre, 0.f);
    __builtin_amdgcn_wave_barrier();
    float mv = 0.f;
#pragma unroll
    for (int j = 0; j < HID; ++j) mv = fmaf(hsh[wave][j], w2r[j], mv);
    atomicMax(&agg[(size_t)d * HID + lane], ordenc(mv));
    __builtin_amdgcn_wave_barrier();
  }
}

// 16 nodes per block: decode agg (empty -> 0, else +b2), out = sigmoid(agg @ Wo + bo)
__global__ __launch_bounds__(256) void out_kernel(
    const unsigned* __restrict__ agg,
    const float* __restrict__ b2,
    const float* __restrict__ Wo, const float* __restrict__ bo,
    float* __restrict__ out, int N)
{
  __shared__ float Wos[HID * OUTF];
  __shared__ float bos[OUTF];
  __shared__ float b2s[HID];
  __shared__ float aggs[16][HID + 1];

  for (int i = threadIdx.x; i < HID * OUTF; i += 256) Wos[i] = Wo[i];
  if (threadIdx.x < OUTF) bos[threadIdx.x] = bo[threadIdx.x];
  if (threadIdx.x < HID) b2s[threadIdx.x] = b2[threadIdx.x];
  __syncthreads();

  const int nodeBase = blockIdx.x * 16;
  {
    int ln = threadIdx.x >> 4;
    int k0 = (threadIdx.x & 15) * 4;
    int n = nodeBase + ln;
    if (n < N) {
      const uint4 u = *(const uint4*)&agg[(size_t)n * HID + k0];
      aggs[ln][k0 + 0] = (u.x == ORD_NEG_INF) ? 0.f : orddec(u.x) + b2s[k0 + 0];
      aggs[ln][k0 + 1] = (u.y == ORD_NEG_INF) ? 0.f : orddec(u.y) + b2s[k0 + 1];
      aggs[ln][k0 + 2] = (u.z == ORD_NEG_INF) ? 0.f : orddec(u.z) + b2s[k0 + 2];
      aggs[ln][k0 + 3] = (u.w == ORD_NEG_INF) ? 0.f : orddec(u.w) + b2s[k0 + 3];
    }
  }
  __syncthreads();
  {
    int ln = threadIdx.x >> 4;
    int o = threadIdx.x & 15;
    int n = nodeBase + ln;
    if (n < N) {
      float acc = bos[o];
#pragma unroll
      for (int k = 0; k < HID; ++k) acc = fmaf(aggs[ln][k], Wos[k * OUTF + o], acc);
      out[n * OUTF + o] = 1.f / (1.f + __expf(-acc));
    }
  }
}

extern "C" void kernel_launch(void* const* d_in, const int* in_sizes, int n_in,
                              void* d_out, int out_size, void* d_ws, size_t ws_size,
                              hipStream_t stream) {
  const float* x  = (const float*)d_in[0];
  const int*   ei = (const int*)d_in[1];
  const float* ea = (const float*)d_in[2];
  const float* W1 = (const float*)d_in[3];
  const float* b1 = (const float*)d_in[4];
  const float* W2 = (const float*)d_in[5];
  const float* b2 = (const float*)d_in[6];
  const float* Wo = (const float*)d_in[7];
  const float* bo = (const float*)d_in[8];
  float* out = (float*)d_out;

  const int N = in_sizes[0] / IN_F;   // 50000
  const int E = in_sizes[1] / 2;      // 1600000

  // ws layout: P(12.8M) | Q fp16(6.4M) | agg(12.8M) | rec N*8*16 uint2(51.2M)
  //          | cnt N*8 i32(1.6M) | ovf_cnt | ovf   -> ~85 MB total (R3-proven)
  char* w = (char*)d_ws;
  float*     Pp  = (float*)w;                    w += (size_t)N * HID * 4;
  _Float16*  Qp  = (_Float16*)w;                 w += (size_t)N * HID * 2;
  unsigned*  agg = (unsigned*)w;                 w += (size_t)N * HID * 4;
  uint2*     rec = (uint2*)w;                    w += (size_t)N * NSUB * SB_CAP * 8;
  int*       cnt = (int*)w;                      w += (size_t)N * NSUB * 4;
  int*   ovf_cnt = (int*)w;                      w += 16;
  int*       ovf = (int*)w;

  hipMemsetAsync(cnt, 0, (size_t)N * NSUB * 4 + 16, stream);

  const int nSB = (E + 1023) / 1024;   // scatter blocks (4 edges/thread)
  pre_scatter_kernel<<<nSB + 512, 256, 0, stream>>>(
      x, ei, ea, W1, b1, Pp, Qp, rec, cnt, ovf, ovf_cnt, E, N, nSB);
  bucket_kernel<<<4096, 256, 0, stream>>>(rec, cnt, W1, W2, Pp, Qp, agg, N);
  overflow_kernel<<<256, 256, 0, stream>>>(ei, ea, W1, W2, Pp, Qp, ovf, ovf_cnt, agg, E);
  out_kernel<<<(N + 15) / 16, 256, 0, stream>>>(agg, b2, Wo, bo, out, N);
}